// Round 2
// baseline (387.745 us; speedup 1.0000x reference)
//
#include <hip/hip_runtime.h>
#include <math.h>

#define SS 2048
#define BB 32
#define HH 1024
#define OCH 16          // o-chunks for split-K vmat
#define OLEN (HH/OCH)   // 64 o per chunk

typedef float v4f __attribute__((ext_vector_type(4)));  // clang-native float4

// Kernel 1 (split-K): vpart[oc][b][h] = sum_{o in chunk} hidden[b,o]*W[o,h]
// grid (OCH, BB) = 512 blocks, block 256. Thread t owns h=4t..4t+3 via float4
// W-row loads (4 KiB contiguous per block per o-step), 64 serial o-steps.
__global__ __launch_bounds__(256) void vmat_kernel(const float* __restrict__ hidden,
                                                   const float* __restrict__ W,
                                                   float* __restrict__ vpart) {
    const int oc = blockIdx.x;
    const int b  = blockIdx.y;
    const int t  = threadIdx.x;
    const float* __restrict__ hrow = hidden + (size_t)b * HH;
    const v4f* __restrict__ Wrow = (const v4f*)W;  // Wrow[o*256 + t]

    v4f acc = (v4f){0.f, 0.f, 0.f, 0.f};
    const int o0 = oc * OLEN;
    #pragma unroll 4
    for (int oo = 0; oo < OLEN; ++oo) {
        const int o = o0 + oo;
        const float hs = hrow[o];               // wave-uniform
        const v4f w = Wrow[(size_t)o * 256 + t];
        acc += hs * w;
    }
    ((v4f*)(vpart + ((size_t)oc * BB + b) * HH))[t] = acc;
}

// Kernel 1b: fold partials -> v[b,h]. grid BB, block 256 (vec4 per thread).
__global__ __launch_bounds__(256) void fold_kernel(const float* __restrict__ vpart,
                                                   float* __restrict__ v) {
    const int b = blockIdx.x;
    const int t = threadIdx.x;
    v4f acc = (v4f){0.f, 0.f, 0.f, 0.f};
    #pragma unroll
    for (int c = 0; c < OCH; ++c)
        acc += ((const v4f*)(vpart + ((size_t)c * BB + b) * HH))[t];
    ((v4f*)(v + (size_t)b * HH))[t] = acc;
}

// Kernel 2: out[b*SS + s] = v[b,:] . enc[s,b,:]
// grid (SS/16, BB) = 4096 blocks, block 256 = 4 waves; each wave does 4
// consecutive s. Lane l holds v[b, 4l..] in 4 float4 regs (reused across 4 s).
// All 16 enc row-loads issued up-front; VGPR capped at 128 via
// __launch_bounds__(256,4) -> 16 waves/CU resident.
// Round-2 change: enc loads are PLAIN cached loads (NT hint removed).
// enc has no reuse, so L2 allocation costs nothing; NT forced every line
// through a full-latency streaming fill path and is the prime suspect for
// the ~1.9 TB/s effective BW (vs ~6.3 achievable).
__global__ __launch_bounds__(256, 4) void score_kernel(const float* __restrict__ enc,
                                                       const float* __restrict__ v,
                                                       float* __restrict__ out) {
    const int b = blockIdx.y;
    const int wave = threadIdx.x >> 6;
    const int lane = threadIdx.x & 63;

    const v4f* __restrict__ vrow = (const v4f*)(v + (size_t)b * HH);
    const v4f v0 = vrow[lane];
    const v4f v1 = vrow[lane + 64];
    const v4f v2 = vrow[lane + 128];
    const v4f v3 = vrow[lane + 192];

    const int s0 = (blockIdx.x * 4 + wave) * 4;       // 4 rows per wave
    const v4f* __restrict__ erow0 =
        (const v4f*)(enc + ((size_t)s0 * BB + b) * HH);
    const size_t sstride = (size_t)BB * HH / 4;       // v4f units between s rows

    // Phase 1: issue all 16 row loads (4 rows x 4 quads), cached.
    v4f e[4][4];
    #pragma unroll
    for (int r = 0; r < 4; ++r) {
        const v4f* __restrict__ p = erow0 + (size_t)r * sstride;
        e[r][0] = p[lane];
        e[r][1] = p[lane + 64];
        e[r][2] = p[lane + 128];
        e[r][3] = p[lane + 192];
    }

    // Phase 2: consume rows in order (oldest load first).
    #pragma unroll
    for (int r = 0; r < 4; ++r) {
        float acc = 0.f;
        acc = fmaf(e[r][0].x, v0.x, acc); acc = fmaf(e[r][0].y, v0.y, acc);
        acc = fmaf(e[r][0].z, v0.z, acc); acc = fmaf(e[r][0].w, v0.w, acc);
        acc = fmaf(e[r][1].x, v1.x, acc); acc = fmaf(e[r][1].y, v1.y, acc);
        acc = fmaf(e[r][1].z, v1.z, acc); acc = fmaf(e[r][1].w, v1.w, acc);
        acc = fmaf(e[r][2].x, v2.x, acc); acc = fmaf(e[r][2].y, v2.y, acc);
        acc = fmaf(e[r][2].z, v2.z, acc); acc = fmaf(e[r][2].w, v2.w, acc);
        acc = fmaf(e[r][3].x, v3.x, acc); acc = fmaf(e[r][3].y, v3.y, acc);
        acc = fmaf(e[r][3].z, v3.z, acc); acc = fmaf(e[r][3].w, v3.w, acc);

        #pragma unroll
        for (int off = 32; off >= 1; off >>= 1)
            acc += __shfl_xor(acc, off, 64);

        if (lane == 0) out[(size_t)b * SS + s0 + r] = acc;
    }
}

// Kernel 3: in-place softmax over s for each b. grid BB, block 256.
__global__ __launch_bounds__(256) void softmax_kernel(float* __restrict__ out) {
    const int b = blockIdx.x;
    float* __restrict__ row = out + (size_t)b * SS;
    const int tid = threadIdx.x;
    const int wave = tid >> 6;
    const int lane = tid & 63;

    float x[8];
    float m = -INFINITY;
    #pragma unroll
    for (int i = 0; i < 8; ++i) {
        x[i] = row[tid + 256 * i];
        m = fmaxf(m, x[i]);
    }
    #pragma unroll
    for (int off = 32; off >= 1; off >>= 1)
        m = fmaxf(m, __shfl_xor(m, off, 64));

    __shared__ float redm[4];
    __shared__ float reds[4];
    if (lane == 0) redm[wave] = m;
    __syncthreads();
    m = fmaxf(fmaxf(redm[0], redm[1]), fmaxf(redm[2], redm[3]));

    float ssum = 0.f;
    #pragma unroll
    for (int i = 0; i < 8; ++i) {
        x[i] = expf(x[i] - m);
        ssum += x[i];
    }
    #pragma unroll
    for (int off = 32; off >= 1; off >>= 1)
        ssum += __shfl_xor(ssum, off, 64);
    if (lane == 0) reds[wave] = ssum;
    __syncthreads();
    ssum = (reds[0] + reds[1]) + (reds[2] + reds[3]);

    const float inv = 1.0f / ssum;
    #pragma unroll
    for (int i = 0; i < 8; ++i)
        row[tid + 256 * i] = x[i] * inv;
}

extern "C" void kernel_launch(void* const* d_in, const int* in_sizes, int n_in,
                              void* d_out, int out_size, void* d_ws, size_t ws_size,
                              hipStream_t stream) {
    const float* hidden = (const float*)d_in[0];   // [B,H]
    const float* enc    = (const float*)d_in[1];   // [S,B,H]
    const float* W      = (const float*)d_in[2];   // [H,H] (out,in)
    // d_in[3] = bias: shifts score[b,:] uniformly -> softmax-invariant, dropped.
    float* out   = (float*)d_out;                  // [B,1,S] flat = [B,S]
    float* vpart = (float*)d_ws;                   // [OCH][B][H] (2 MiB)
    float* v     = vpart + (size_t)OCH * BB * HH;  // [B][H] (128 KiB)

    vmat_kernel<<<dim3(OCH, BB), 256, 0, stream>>>(hidden, W, vpart);
    fold_kernel<<<BB, 256, 0, stream>>>(vpart, v);
    score_kernel<<<dim3(SS / 16, BB), 256, 0, stream>>>(enc, v, out);
    softmax_kernel<<<BB, 256, 0, stream>>>(out);
}

// Round 3
// 353.206 us; speedup vs baseline: 1.0978x; 1.0978x over previous
//
#include <hip/hip_runtime.h>
#include <math.h>

#define SS 2048
#define BB 32
#define HH 1024
#define OCH 16          // o-chunks for split-K vmat
#define OLEN (HH/OCH)   // 64 o per chunk

typedef float v4f __attribute__((ext_vector_type(4)));  // clang-native float4

// Kernel 1 (split-K): vpart[oc][b][h] = sum_{o in chunk} hidden[b,o]*W[o,h]
// grid (OCH, BB) = 512 blocks, block 256. Thread t owns h=4t..4t+3 via float4
// W-row loads (4 KiB contiguous per block per o-step), 64 serial o-steps.
__global__ __launch_bounds__(256) void vmat_kernel(const float* __restrict__ hidden,
                                                   const float* __restrict__ W,
                                                   float* __restrict__ vpart) {
    const int oc = blockIdx.x;
    const int b  = blockIdx.y;
    const int t  = threadIdx.x;
    const float* __restrict__ hrow = hidden + (size_t)b * HH;
    const v4f* __restrict__ Wrow = (const v4f*)W;  // Wrow[o*256 + t]

    v4f acc = (v4f){0.f, 0.f, 0.f, 0.f};
    const int o0 = oc * OLEN;
    #pragma unroll 4
    for (int oo = 0; oo < OLEN; ++oo) {
        const int o = o0 + oo;
        const float hs = hrow[o];               // wave-uniform
        const v4f w = Wrow[(size_t)o * 256 + t];
        acc += hs * w;
    }
    ((v4f*)(vpart + ((size_t)oc * BB + b) * HH))[t] = acc;
}

// Kernel 1b: fold partials -> v[b,h]. grid BB, block 256 (vec4 per thread).
__global__ __launch_bounds__(256) void fold_kernel(const float* __restrict__ vpart,
                                                   float* __restrict__ v) {
    const int b = blockIdx.x;
    const int t = threadIdx.x;
    v4f acc = (v4f){0.f, 0.f, 0.f, 0.f};
    #pragma unroll
    for (int c = 0; c < OCH; ++c)
        acc += ((const v4f*)(vpart + ((size_t)c * BB + b) * HH))[t];
    ((v4f*)(v + (size_t)b * HH))[t] = acc;
}

// Kernel 2: out[b*SS + s] = v[b,:] . enc[s,b,:]
// Round-3 change: grid TRANSPOSED to (BB, SS/16) -> blockIdx.x = b (fastest).
// With x=s-chunk (old), the ~512 co-resident blocks spanned only 4 of 32 b
// values, so the live enc addresses touched 16 KiB of every 128 KiB panel
// (addr bits [12:16] restricted) -> HBM channel imbalance -> ~1.7 TB/s.
// With x=b, concurrent blocks cover ALL 32 b for consecutive s-chunks:
// dense contiguous 128 KiB panels, full channel coverage.
// NT loads kept (R2 showed plain loads cost +32 us).
__global__ __launch_bounds__(256, 4) void score_kernel(const float* __restrict__ enc,
                                                       const float* __restrict__ v,
                                                       float* __restrict__ out) {
    const int b = blockIdx.x;
    const int wave = threadIdx.x >> 6;
    const int lane = threadIdx.x & 63;

    const v4f* __restrict__ vrow = (const v4f*)(v + (size_t)b * HH);
    const v4f v0 = vrow[lane];
    const v4f v1 = vrow[lane + 64];
    const v4f v2 = vrow[lane + 128];
    const v4f v3 = vrow[lane + 192];

    const int s0 = (blockIdx.y * 4 + wave) * 4;       // 4 rows per wave
    const v4f* __restrict__ erow0 =
        (const v4f*)(enc + ((size_t)s0 * BB + b) * HH);
    const size_t sstride = (size_t)BB * HH / 4;       // v4f units between s rows

    // Phase 1: issue all 16 non-temporal loads (4 rows x 4 quads).
    v4f e[4][4];
    #pragma unroll
    for (int r = 0; r < 4; ++r) {
        const v4f* __restrict__ p = erow0 + (size_t)r * sstride;
        e[r][0] = __builtin_nontemporal_load(&p[lane]);
        e[r][1] = __builtin_nontemporal_load(&p[lane + 64]);
        e[r][2] = __builtin_nontemporal_load(&p[lane + 128]);
        e[r][3] = __builtin_nontemporal_load(&p[lane + 192]);
    }

    // Phase 2: consume rows in order (oldest load first).
    #pragma unroll
    for (int r = 0; r < 4; ++r) {
        float acc = 0.f;
        acc = fmaf(e[r][0].x, v0.x, acc); acc = fmaf(e[r][0].y, v0.y, acc);
        acc = fmaf(e[r][0].z, v0.z, acc); acc = fmaf(e[r][0].w, v0.w, acc);
        acc = fmaf(e[r][1].x, v1.x, acc); acc = fmaf(e[r][1].y, v1.y, acc);
        acc = fmaf(e[r][1].z, v1.z, acc); acc = fmaf(e[r][1].w, v1.w, acc);
        acc = fmaf(e[r][2].x, v2.x, acc); acc = fmaf(e[r][2].y, v2.y, acc);
        acc = fmaf(e[r][2].z, v2.z, acc); acc = fmaf(e[r][2].w, v2.w, acc);
        acc = fmaf(e[r][3].x, v3.x, acc); acc = fmaf(e[r][3].y, v3.y, acc);
        acc = fmaf(e[r][3].z, v3.z, acc); acc = fmaf(e[r][3].w, v3.w, acc);

        #pragma unroll
        for (int off = 32; off >= 1; off >>= 1)
            acc += __shfl_xor(acc, off, 64);

        if (lane == 0) out[(size_t)b * SS + s0 + r] = acc;
    }
}

// Kernel 3: in-place softmax over s for each b. grid BB, block 256.
__global__ __launch_bounds__(256) void softmax_kernel(float* __restrict__ out) {
    const int b = blockIdx.x;
    float* __restrict__ row = out + (size_t)b * SS;
    const int tid = threadIdx.x;
    const int wave = tid >> 6;
    const int lane = tid & 63;

    float x[8];
    float m = -INFINITY;
    #pragma unroll
    for (int i = 0; i < 8; ++i) {
        x[i] = row[tid + 256 * i];
        m = fmaxf(m, x[i]);
    }
    #pragma unroll
    for (int off = 32; off >= 1; off >>= 1)
        m = fmaxf(m, __shfl_xor(m, off, 64));

    __shared__ float redm[4];
    __shared__ float reds[4];
    if (lane == 0) redm[wave] = m;
    __syncthreads();
    m = fmaxf(fmaxf(redm[0], redm[1]), fmaxf(redm[2], redm[3]));

    float ssum = 0.f;
    #pragma unroll
    for (int i = 0; i < 8; ++i) {
        x[i] = expf(x[i] - m);
        ssum += x[i];
    }
    #pragma unroll
    for (int off = 32; off >= 1; off >>= 1)
        ssum += __shfl_xor(ssum, off, 64);
    if (lane == 0) reds[wave] = ssum;
    __syncthreads();
    ssum = (reds[0] + reds[1]) + (reds[2] + reds[3]);

    const float inv = 1.0f / ssum;
    #pragma unroll
    for (int i = 0; i < 8; ++i)
        row[tid + 256 * i] = x[i] * inv;
}

extern "C" void kernel_launch(void* const* d_in, const int* in_sizes, int n_in,
                              void* d_out, int out_size, void* d_ws, size_t ws_size,
                              hipStream_t stream) {
    const float* hidden = (const float*)d_in[0];   // [B,H]
    const float* enc    = (const float*)d_in[1];   // [S,B,H]
    const float* W      = (const float*)d_in[2];   // [H,H] (out,in)
    // d_in[3] = bias: shifts score[b,:] uniformly -> softmax-invariant, dropped.
    float* out   = (float*)d_out;                  // [B,1,S] flat = [B,S]
    float* vpart = (float*)d_ws;                   // [OCH][B][H] (2 MiB)
    float* v     = vpart + (size_t)OCH * BB * HH;  // [B][H] (128 KiB)

    vmat_kernel<<<dim3(OCH, BB), 256, 0, stream>>>(hidden, W, vpart);
    fold_kernel<<<BB, 256, 0, stream>>>(vpart, v);
    score_kernel<<<dim3(BB, SS / 16), 256, 0, stream>>>(enc, v, out);
    softmax_kernel<<<BB, 256, 0, stream>>>(out);
}